// Round 3
// baseline (505.477 us; speedup 1.0000x reference)
//
#include <hip/hip_runtime.h>

// GODE on MI355X. Internal compute: bf16 MFMA, fp32 accum. h kept TRANSPOSED:
// hT[(b*128+d)][n] so adj@h is gemm_bt (both operands row-major, contiguous k) and the
// @W GEMM fuses into the epilogue (128-row m-tile == one batch's full d-range).
// Input/output dtype (f32 vs bf16) is RUNTIME-DETECTED from x's raw u16 words:
// bf16 N(0,1) words decode to |v|<6; f32 low-mantissa words decode to |v|>2^64 w.p. ~1.
// Boundary kernels branch on the flag; core GEMMs are dtype-invariant (bf16 in ws).

typedef unsigned short u16;
typedef unsigned int   u32;
typedef unsigned long long u64;
typedef __attribute__((ext_vector_type(8))) short bf8;  // 8 raw bf16 (4 VGPRs)
typedef __attribute__((ext_vector_type(4))) float f4;

#define AS1 __attribute__((address_space(1)))
#define AS3 __attribute__((address_space(3)))

__device__ __forceinline__ void gl_lds16(const void* g, void* l) {
  __builtin_amdgcn_global_load_lds((const AS1 u32*)g, (AS3 u32*)l, 16, 0, 0);
}
__device__ __forceinline__ float bf2f(u16 v) {
  u32 u = ((u32)v) << 16; return __builtin_bit_cast(float, u);
}
__device__ __forceinline__ u16 f2bf(float f) {  // RNE
  u32 u = __builtin_bit_cast(u32, f);
  return (u16)((u + 0x7fffu + ((u >> 16) & 1u)) >> 16);
}
// dtype-flag-aware scalar read (flag: 1=f32, 0=bf16)
__device__ __forceinline__ float ldf(const void* p, size_t i, u32 isf32) {
  return isf32 ? ((const float*)p)[i] : bf2f(((const u16*)p)[i]);
}

// Stage a 128-row x 32-col bf16 tile (row stride `stride` elems) into LDS [128][32].
__device__ __forceinline__ void stage128x32(const u16* grow0, int stride, u16* lds,
                                            int wave, int lane) {
  int r0 = wave * 16 + (lane >> 2);
  int c0 = (lane & 3) * 8;
  gl_lds16(grow0 + (size_t)r0 * stride + c0, lds + wave * 512);
  gl_lds16(grow0 + (size_t)(64 + r0) * stride + c0, lds + 2048 + wave * 512);
}

// ---------------- dtype detection ----------------
__global__ void detect_dtype(const u16* __restrict__ x_raw, u32* __restrict__ flag) {
  __shared__ int s;
  int tid = threadIdx.x;
  if (tid == 0) s = 0;
  __syncthreads();
  int huge = 0;
#pragma unroll
  for (int j = 0; j < 16; ++j) {
    u16 v = x_raw[tid * 16 + j];
    u32 e = (v >> 7) & 0xFF;          // bf16 exponent field
    if (e >= 0xC0) huge = 1;          // |v| >= 2^64: impossible for N(0,1) bf16
  }
  if (huge) atomicOr(&s, 1);
  __syncthreads();
  if (tid == 0) flag[0] = (u32)s;     // 1 = f32 inputs, 0 = bf16 inputs
}

// ---------------- generic convert to bf16 (4 elems/thread) ----------------
__global__ void cvt_bf16(const void* __restrict__ in, u16* __restrict__ out,
                         long in_off, int n, const u32* __restrict__ flag) {
  u32 isf32 = flag[0];
  int gid = blockIdx.x * 256 + threadIdx.x;
  long i = in_off + (long)gid * 4;
  if (gid * 4 >= n) return;
  u16 o0, o1, o2, o3;
  if (isf32) {
    f4 v = *(const f4*)&((const float*)in)[i];
    o0 = f2bf(v[0]); o1 = f2bf(v[1]); o2 = f2bf(v[2]); o3 = f2bf(v[3]);
  } else {
    u64 v = *(const u64*)&((const u16*)in)[i];
    o0 = (u16)v; o1 = (u16)(v >> 16); o2 = (u16)(v >> 32); o3 = (u16)(v >> 48);
  }
  u64 pk = (u64)o0 | ((u64)o1 << 16) | ((u64)o2 << 32) | ((u64)o3 << 48);
  *(u64*)&out[(size_t)gid * 4] = pk;
}

// ---------------- weight pre-transpose (tiny, dtype-aware) ----------------
// WaT[256][256]=Wa^T, WbT[128][256]=Wb^T, W1T[64][128]=W1[:, :64]^T, W2T[64][128]=W2[:, 64:]^T
__global__ void prep_weights(const void* __restrict__ Wa, const void* __restrict__ Wb,
                             const void* __restrict__ W1, const void* __restrict__ W2,
                             u16* __restrict__ WaT, u16* __restrict__ WbT,
                             u16* __restrict__ W1T, u16* __restrict__ W2T,
                             const u32* __restrict__ flag) {
  u32 isf32 = flag[0];
  int i = blockIdx.x * 256 + threadIdx.x;
  if (i < 65536) {
    int o = i >> 8, k = i & 255; WaT[o * 256 + k] = f2bf(ldf(Wa, (size_t)k * 256 + o, isf32));
  } else if (i < 98304) {
    int j = i - 65536; int o = j >> 8, k = j & 255;
    WbT[o * 256 + k] = f2bf(ldf(Wb, (size_t)k * 128 + o, isf32));
  } else if (i < 106496) {
    int j = i - 98304; int jj = j >> 7, k = j & 127;
    W1T[jj * 128 + k] = f2bf(ldf(W1, (size_t)k * 128 + jj, isf32));
  } else {
    int j = i - 106496; int jj = j >> 7, k = j & 127;
    W2T[jj * 128 + k] = f2bf(ldf(W2, (size_t)k * 128 + 64 + jj, isf32));
  }
}

// ---------------- MLP GEMM 1 (chunked): Z1 = relu([x,hz] @ Wa + ba) ----------------
// Rows are chunk-local (16384/chunk). K=256: k<128 from xb, else hzb (bf16, stride 128).
__global__ __launch_bounds__(256, 2) void mlp1(const u16* __restrict__ xb,
                                               const u16* __restrict__ hzb,
                                               const u16* __restrict__ WaT,
                                               const void* __restrict__ ba,
                                               u16* __restrict__ Z1,
                                               const u32* __restrict__ flag) {
  __shared__ __align__(16) u16 lA[128 * 32];
  __shared__ __align__(16) u16 lB[128 * 32];
  u32 isf32 = flag[0];
  int tid = threadIdx.x, lane = tid & 63, wave = tid >> 6;
  int wm = wave >> 1, wn = wave & 1, col = lane & 15, quad = lane >> 4;
  int r0 = blockIdx.y * 128;   // chunk-local row
  int o0 = blockIdx.x * 128;

  f4 acc[4][4] = {};
  for (int kk = 0; kk < 8; ++kk) {
    int k0 = kk * 32;
    const u16* Asrc = (k0 < 128) ? (xb + (size_t)r0 * 128 + k0)
                                 : (hzb + (size_t)r0 * 128 + (k0 - 128));
    __syncthreads();
    stage128x32(Asrc, 128, lA, wave, lane);
    stage128x32(WaT + (size_t)o0 * 256 + k0, 256, lB, wave, lane);
    __syncthreads();
    bf8 af[4], bfr[4];
#pragma unroll
    for (int mi = 0; mi < 4; ++mi) af[mi] = *(const bf8*)&lA[(wm * 64 + mi * 16 + col) * 32 + quad * 8];
#pragma unroll
    for (int nj = 0; nj < 4; ++nj) bfr[nj] = *(const bf8*)&lB[(wn * 64 + nj * 16 + col) * 32 + quad * 8];
#pragma unroll
    for (int mi = 0; mi < 4; ++mi)
#pragma unroll
      for (int nj = 0; nj < 4; ++nj)
        acc[mi][nj] = __builtin_amdgcn_mfma_f32_16x16x32_bf16(af[mi], bfr[nj], acc[mi][nj], 0, 0, 0);
  }
#pragma unroll
  for (int mi = 0; mi < 4; ++mi)
#pragma unroll
    for (int nj = 0; nj < 4; ++nj) {
      int o = o0 + wn * 64 + nj * 16 + col;
      float bav = ldf(ba, o, isf32);
      int rb = r0 + wm * 64 + mi * 16 + quad * 4;
#pragma unroll
      for (int r = 0; r < 4; ++r) {
        float v = acc[mi][nj][r] + bav;
        Z1[(size_t)(rb + r) * 256 + o] = f2bf(fmaxf(v, 0.f));
      }
    }
}

// ---------------- MLP GEMM 2 (chunked): h0 = tanh(Z1 @ Wb + bb), written TRANSPOSED ----
__global__ __launch_bounds__(256, 2) void mlp2(const u16* __restrict__ Z1,
                                               const u16* __restrict__ WbT,
                                               const void* __restrict__ bb,
                                               u16* __restrict__ hT,
                                               int rbase, const u32* __restrict__ flag) {
  __shared__ __align__(16) u16 lA[128 * 32];
  __shared__ __align__(16) u16 lB[128 * 32];
  u32 isf32 = flag[0];
  int tid = threadIdx.x, lane = tid & 63, wave = tid >> 6;
  int wm = wave >> 1, wn = wave & 1, col = lane & 15, quad = lane >> 4;
  int r0 = blockIdx.x * 128;   // chunk-local row

  f4 acc[4][4] = {};
  for (int kk = 0; kk < 8; ++kk) {
    int k0 = kk * 32;
    __syncthreads();
    stage128x32(Z1 + (size_t)r0 * 256 + k0, 256, lA, wave, lane);
    stage128x32(WbT + k0, 256, lB, wave, lane);
    __syncthreads();
    bf8 af[4], bfr[4];
#pragma unroll
    for (int mi = 0; mi < 4; ++mi) af[mi] = *(const bf8*)&lA[(wm * 64 + mi * 16 + col) * 32 + quad * 8];
#pragma unroll
    for (int nj = 0; nj < 4; ++nj) bfr[nj] = *(const bf8*)&lB[(wn * 64 + nj * 16 + col) * 32 + quad * 8];
#pragma unroll
    for (int mi = 0; mi < 4; ++mi)
#pragma unroll
      for (int nj = 0; nj < 4; ++nj)
        acc[mi][nj] = __builtin_amdgcn_mfma_f32_16x16x32_bf16(af[mi], bfr[nj], acc[mi][nj], 0, 0, 0);
  }
#pragma unroll
  for (int mi = 0; mi < 4; ++mi)
#pragma unroll
    for (int nj = 0; nj < 4; ++nj) {
      int d = wn * 64 + nj * 16 + col;
      float bbv = ldf(bb, d, isf32);
      int rabs = rbase + r0 + wm * 64 + mi * 16 + quad * 4;  // 4 consecutive rows, same b
      int b = rabs >> 11, n = rabs & 2047;
      u16 p[4];
#pragma unroll
      for (int r = 0; r < 4; ++r) p[r] = f2bf(tanhf(acc[mi][nj][r] + bbv));
      u64 pk = (u64)p[0] | ((u64)p[1] << 16) | ((u64)p[2] << 32) | ((u64)p[3] << 48);
      *(u64*)&hT[(size_t)(b * 128 + d) * 2048 + n] = pk;
    }
}

// ---------------- fused diffusion step ----------------
// Pass 1 (gemm_bt): G_T[c=(b,d)][n2] = sum_k hin[c][k] * adjb[n2][k]   (128x128 tile, K=2048)
// Pass 2 (in-LDS):  M[j][n] = sum_d WT[j][d] * G_T[b*128+d][n]         (K=128)
// Epilogue: nh = hold + DT*tanh(M); (eps step: nh *= clip(eps,0,0.1)); write half;
//           copy untouched half (ping-pong buffers avoid cross-block RAW race).
__global__ __launch_bounds__(256, 2) void fused_step(const u16* __restrict__ hin,
                                                     const u16* __restrict__ adjb,
                                                     const u16* __restrict__ WT,
                                                     const void* __restrict__ eps,
                                                     u16* __restrict__ hout,
                                                     int half, const u32* __restrict__ flag) {
  __shared__ __align__(16) u16 lA[128 * 32];
  __shared__ __align__(16) u16 lB[128 * 32];
  __shared__ __align__(16) u16 gT[128 * 136];
  u32 isf32 = flag[0];
  int tid = threadIdx.x, lane = tid & 63, wave = tid >> 6;
  int wm = wave >> 1, wn = wave & 1, col = lane & 15, quad = lane >> 4;
  int b = blockIdx.y;
  int n0 = blockIdx.x * 128;

  const u16* Arow = hin + (size_t)(b * 128) * 2048;
  const u16* Brow = adjb + (size_t)n0 * 2048;

  f4 acc[4][4] = {};
  for (int kk = 0; kk < 64; ++kk) {
    __syncthreads();
    stage128x32(Arow + kk * 32, 2048, lA, wave, lane);
    stage128x32(Brow + kk * 32, 2048, lB, wave, lane);
    __syncthreads();
    bf8 af[4], bfr[4];
#pragma unroll
    for (int mi = 0; mi < 4; ++mi) af[mi] = *(const bf8*)&lA[(wm * 64 + mi * 16 + col) * 32 + quad * 8];
#pragma unroll
    for (int nj = 0; nj < 4; ++nj) bfr[nj] = *(const bf8*)&lB[(wn * 64 + nj * 16 + col) * 32 + quad * 8];
#pragma unroll
    for (int mi = 0; mi < 4; ++mi)
#pragma unroll
      for (int nj = 0; nj < 4; ++nj)
        acc[mi][nj] = __builtin_amdgcn_mfma_f32_16x16x32_bf16(af[mi], bfr[nj], acc[mi][nj], 0, 0, 0);
  }
  __syncthreads();
#pragma unroll
  for (int mi = 0; mi < 4; ++mi)
#pragma unroll
    for (int nj = 0; nj < 4; ++nj) {
      int d0 = wm * 64 + mi * 16 + quad * 4;
      int nl = wn * 64 + nj * 16 + col;
      u32 lo = (u32)f2bf(acc[mi][nj][0]) | ((u32)f2bf(acc[mi][nj][1]) << 16);
      u32 hi = (u32)f2bf(acc[mi][nj][2]) | ((u32)f2bf(acc[mi][nj][3]) << 16);
      *(u64*)&gT[nl * 136 + d0] = (u64)lo | ((u64)hi << 32);
    }
  __syncthreads();

  f4 acc2[4][2] = {};
#pragma unroll
  for (int k2 = 0; k2 < 4; ++k2) {
    bf8 aw[4], bg[2];
#pragma unroll
    for (int mi = 0; mi < 4; ++mi)
      aw[mi] = *(const bf8*)&WT[(size_t)(mi * 16 + col) * 128 + k2 * 32 + quad * 8];
#pragma unroll
    for (int nj = 0; nj < 2; ++nj)
      bg[nj] = *(const bf8*)&gT[(wave * 32 + nj * 16 + col) * 136 + k2 * 32 + quad * 8];
#pragma unroll
    for (int mi = 0; mi < 4; ++mi)
#pragma unroll
      for (int nj = 0; nj < 2; ++nj)
        acc2[mi][nj] = __builtin_amdgcn_mfma_f32_16x16x32_bf16(aw[mi], bg[nj], acc2[mi][nj], 0, 0, 0);
  }

  bool has_eps = (eps != nullptr);
#pragma unroll
  for (int mi = 0; mi < 4; ++mi)
#pragma unroll
    for (int nj = 0; nj < 2; ++nj) {
      int j0 = mi * 16 + quad * 4;
      int nl = wave * 32 + nj * 16 + col;
      int n = n0 + nl;
      float ev[4];
      if (has_eps) {
        size_t eoff = ((size_t)b * 2048 + n) * 64 + j0;
        if (isf32) {
          f4 e = *(const f4*)&((const float*)eps)[eoff];
          ev[0] = e[0]; ev[1] = e[1]; ev[2] = e[2]; ev[3] = e[3];
        } else {
          u64 e = *(const u64*)&((const u16*)eps)[eoff];
          ev[0] = bf2f((u16)e); ev[1] = bf2f((u16)(e >> 16));
          ev[2] = bf2f((u16)(e >> 32)); ev[3] = bf2f((u16)(e >> 48));
        }
      }
#pragma unroll
      for (int r = 0; r < 4; ++r) {
        int j = j0 + r;
        size_t idx = (size_t)(b * 128 + half * 64 + j) * 2048 + n;
        float hold = bf2f(hin[idx]);
        float nh = hold + 0.01f * tanhf(acc2[mi][nj][r]);
        if (has_eps) {
          float e = fminf(fmaxf(ev[r], 0.f), 0.1f);  // clip in fp32
          nh = e * nh;
        }
        hout[idx] = f2bf(nh);
      }
    }

  // copy the untouched half for this (b, n-tile)
  {
    int oh = (1 - half) * 64;
    const u16* src = hin + (size_t)(b * 128 + oh) * 2048 + n0;
    u16* dst = hout + (size_t)(b * 128 + oh) * 2048 + n0;
#pragma unroll
    for (int i = 0; i < 4; ++i) {
      int idx = i * 256 + tid;
      int rr = idx >> 4;
      int cc = (idx & 15) * 8;
      *(uint4*)&dst[(size_t)rr * 2048 + cc] = *(const uint4*)&src[(size_t)rr * 2048 + cc];
    }
  }
}

// ---------------- final un-transpose: out[b][n][d] = hT[(b*128+d)][n], dtype-aware ----
__global__ void untranspose(const u16* __restrict__ hT, void* __restrict__ out,
                            const u32* __restrict__ flag) {
  __shared__ __align__(16) u16 t[64][65];
  u32 isf32 = flag[0];
  int b = blockIdx.z, d0 = blockIdx.y * 64, n0 = blockIdx.x * 64;
  int tid = threadIdx.x;
#pragma unroll
  for (int i = 0; i < 16; ++i) {
    int idx = tid + i * 256;
    int r = idx >> 6, c = idx & 63;
    t[r][c] = hT[(size_t)(b * 128 + d0 + r) * 2048 + n0 + c];
  }
  __syncthreads();
#pragma unroll
  for (int i = 0; i < 16; ++i) {
    int idx = tid + i * 256;
    int r = idx >> 6, c = idx & 63;  // r = n-local, c = d-local
    size_t o = (size_t)(b * 2048 + n0 + r) * 128 + d0 + c;
    if (isf32) ((float*)out)[o] = bf2f(t[c][r]);
    else       ((u16*)out)[o] = t[c][r];
  }
}

extern "C" void kernel_launch(void* const* d_in, const int* in_sizes, int n_in,
                              void* d_out, int out_size, void* d_ws, size_t ws_size,
                              hipStream_t stream) {
  const void* x   = d_in[0];
  const void* hz  = d_in[1];
  const void* adj = d_in[2];
  const void* W1  = d_in[3];
  const void* W2  = d_in[4];
  const void* Wa  = d_in[5];
  const void* ba  = d_in[6];
  const void* Wb  = d_in[7];
  const void* bb  = d_in[8];
  const void* eps = d_in[9];

  // workspace layout (46 MB + 4B):
  //   hA   @  0M   16.78 MB  transposed h ping buffer (bf16 [4096][2048])
  //   xcb  @ 17M    4.20 MB  x chunk bf16   (16384 x 128)
  //   hzcb @ 22M    4.20 MB  hz chunk bf16
  //   Z1c  @ 27M    8.39 MB  MLP hidden chunk (16384 x 256)
  //   adjb @ 36M    8.39 MB  adj bf16 [2048][2048]
  //   WaT/WbT/W1T/W2T @ 45M  (229 KB)
  //   flag @ 46M    4 B
  // hB (pong) = d_out scratch (>=16.78MB in both dtypes); untranspose rewrites d_out at end.
  char* ws = (char*)d_ws;
  u16* hA   = (u16*)(ws);
  u16* xcb  = (u16*)(ws + (17ull << 20));
  u16* hzcb = (u16*)(ws + (22ull << 20));
  u16* Z1c  = (u16*)(ws + (27ull << 20));
  u16* adjb = (u16*)(ws + (36ull << 20));
  u16* WaT  = (u16*)(ws + (45ull << 20));
  u16* WbT  = WaT + 256 * 256;
  u16* W1T  = WbT + 128 * 256;
  u16* W2T  = W1T + 64 * 128;
  u32* flag = (u32*)(ws + (46ull << 20));
  u16* hB   = (u16*)d_out;

  detect_dtype<<<dim3(1), dim3(256), 0, stream>>>((const u16*)x, flag);
  prep_weights<<<dim3(448), dim3(256), 0, stream>>>(Wa, Wb, W1, W2, WaT, WbT, W1T, W2T, flag);
  cvt_bf16<<<dim3(4096), dim3(256), 0, stream>>>(adj, adjb, 0, 4194304, flag);

  // MLP in 4 chunks of 16384 rows (stream order serializes chunk-buffer reuse)
  for (int c = 0; c < 4; ++c) {
    long off = (long)c * 16384 * 128;
    cvt_bf16<<<dim3(2048), dim3(256), 0, stream>>>(x,  xcb,  off, 2097152, flag);
    cvt_bf16<<<dim3(2048), dim3(256), 0, stream>>>(hz, hzcb, off, 2097152, flag);
    mlp1<<<dim3(2, 128), dim3(256), 0, stream>>>(xcb, hzcb, WaT, ba, Z1c, flag);
    mlp2<<<dim3(128), dim3(256), 0, stream>>>(Z1c, WbT, bb, hA, c * 16384, flag);
  }
  // iter 1
  fused_step<<<dim3(16, 32), dim3(256), 0, stream>>>(hA, adjb, W1T, nullptr, hB, 0, flag);
  fused_step<<<dim3(16, 32), dim3(256), 0, stream>>>(hB, adjb, W2T, eps, hA, 1, flag);
  // iter 2
  fused_step<<<dim3(16, 32), dim3(256), 0, stream>>>(hA, adjb, W1T, nullptr, hB, 0, flag);
  fused_step<<<dim3(16, 32), dim3(256), 0, stream>>>(hB, adjb, W2T, eps, hA, 1, flag);
  untranspose<<<dim3(32, 2, 32), dim3(256), 0, stream>>>(hA, d_out, flag);
}

// Round 4
// 412.112 us; speedup vs baseline: 1.2266x; 1.2266x over previous
//
#include <hip/hip_runtime.h>

// GODE on MI355X. Internal compute: bf16 MFMA, fp32 accum. h kept TRANSPOSED:
// hT[(b*128+d)][n] so adj@h is gemm_bt (both operands row-major, contiguous k) and the
// @W GEMM fuses into the epilogue (128-row m-tile == one batch's full d-range).
// Input/output dtype (f32 vs bf16) runtime-detected; boundary kernels branch, core bf16.
// R4: (a) fused_step K-loop double-buffered (latency-bound at 2 blocks/CU: issue next
// global_load_lds before compute so the barrier drain overlaps MFMA); (b) whole MLP
// fused into one kernel (direct f32 reads, Z in LDS, no Z1 global round-trip).

typedef unsigned short u16;
typedef unsigned int   u32;
typedef unsigned long long u64;
typedef __attribute__((ext_vector_type(8))) short bf8;  // 8 raw bf16 (4 VGPRs)
typedef __attribute__((ext_vector_type(4))) float f4;

#define AS1 __attribute__((address_space(1)))
#define AS3 __attribute__((address_space(3)))

__device__ __forceinline__ void gl_lds16(const void* g, void* l) {
  __builtin_amdgcn_global_load_lds((const AS1 u32*)g, (AS3 u32*)l, 16, 0, 0);
}
__device__ __forceinline__ float bf2f(u16 v) {
  u32 u = ((u32)v) << 16; return __builtin_bit_cast(float, u);
}
__device__ __forceinline__ u16 f2bf(float f) {  // RNE
  u32 u = __builtin_bit_cast(u32, f);
  return (u16)((u + 0x7fffu + ((u >> 16) & 1u)) >> 16);
}
__device__ __forceinline__ float ldf(const void* p, size_t i, u32 isf32) {
  return isf32 ? ((const float*)p)[i] : bf2f(((const u16*)p)[i]);
}

// Stage a 128-row x 32-col bf16 tile (row stride `stride` elems) into LDS [128][32].
__device__ __forceinline__ void stage128x32(const u16* grow0, int stride, u16* lds,
                                            int wave, int lane) {
  int r0 = wave * 16 + (lane >> 2);
  int c0 = (lane & 3) * 8;
  gl_lds16(grow0 + (size_t)r0 * stride + c0, lds + wave * 512);
  gl_lds16(grow0 + (size_t)(64 + r0) * stride + c0, lds + 2048 + wave * 512);
}

// ---------------- dtype detection ----------------
__global__ void detect_dtype(const u16* __restrict__ x_raw, u32* __restrict__ flag) {
  __shared__ int s;
  int tid = threadIdx.x;
  if (tid == 0) s = 0;
  __syncthreads();
  int huge = 0;
#pragma unroll
  for (int j = 0; j < 16; ++j) {
    u16 v = x_raw[tid * 16 + j];
    u32 e = (v >> 7) & 0xFF;
    if (e >= 0xC0) huge = 1;          // |v| >= 2^64: impossible for N(0,1) bf16
  }
  if (huge) atomicOr(&s, 1);
  __syncthreads();
  if (tid == 0) flag[0] = (u32)s;     // 1 = f32 inputs, 0 = bf16 inputs
}

// ---------------- generic convert to bf16 (adj only now) ----------------
__global__ void cvt_bf16(const void* __restrict__ in, u16* __restrict__ out,
                         long in_off, int n, const u32* __restrict__ flag) {
  u32 isf32 = flag[0];
  int gid = blockIdx.x * 256 + threadIdx.x;
  long i = in_off + (long)gid * 4;
  if (gid * 4 >= n) return;
  u16 o0, o1, o2, o3;
  if (isf32) {
    f4 v = *(const f4*)&((const float*)in)[i];
    o0 = f2bf(v[0]); o1 = f2bf(v[1]); o2 = f2bf(v[2]); o3 = f2bf(v[3]);
  } else {
    u64 v = *(const u64*)&((const u16*)in)[i];
    o0 = (u16)v; o1 = (u16)(v >> 16); o2 = (u16)(v >> 32); o3 = (u16)(v >> 48);
  }
  u64 pk = (u64)o0 | ((u64)o1 << 16) | ((u64)o2 << 32) | ((u64)o3 << 48);
  *(u64*)&out[(size_t)gid * 4] = pk;
}

// ---------------- weight pre-transpose (tiny, dtype-aware) ----------------
__global__ void prep_weights(const void* __restrict__ Wa, const void* __restrict__ Wb,
                             const void* __restrict__ W1, const void* __restrict__ W2,
                             u16* __restrict__ WaT, u16* __restrict__ WbT,
                             u16* __restrict__ W1T, u16* __restrict__ W2T,
                             const u32* __restrict__ flag) {
  u32 isf32 = flag[0];
  int i = blockIdx.x * 256 + threadIdx.x;
  if (i < 65536) {
    int o = i >> 8, k = i & 255; WaT[o * 256 + k] = f2bf(ldf(Wa, (size_t)k * 256 + o, isf32));
  } else if (i < 98304) {
    int j = i - 65536; int o = j >> 8, k = j & 255;
    WbT[o * 256 + k] = f2bf(ldf(Wb, (size_t)k * 128 + o, isf32));
  } else if (i < 106496) {
    int j = i - 98304; int jj = j >> 7, k = j & 127;
    W1T[jj * 128 + k] = f2bf(ldf(W1, (size_t)k * 128 + jj, isf32));
  } else {
    int j = i - 106496; int jj = j >> 7, k = j & 127;
    W2T[jj * 128 + k] = f2bf(ldf(W2, (size_t)k * 128 + 64 + jj, isf32));
  }
}

// ---------------- fused MLP: hT = tanh(relu([x,hz]@Wa+ba)@Wb+bb), transposed store ----
// 64 rows/block, grid 1024. Z (64x256 bf16, stride 264 for conflict-free phase-2 reads)
// lives in LDS; x/hz read directly (dtype-branched convert in the A-stage).
__global__ __launch_bounds__(256, 2) void mlp_fused(const void* __restrict__ x,
                                                    const void* __restrict__ hz,
                                                    const u16* __restrict__ WaT,
                                                    const void* __restrict__ ba,
                                                    const u16* __restrict__ WbT,
                                                    const void* __restrict__ bb,
                                                    u16* __restrict__ hT,
                                                    const u32* __restrict__ flag) {
  __shared__ __align__(16) u16 Z[64 * 264];   // 33.8 KB
  __shared__ __align__(16) u16 lA[64 * 32];   // 4 KB
  __shared__ __align__(16) u16 lB[256 * 32];  // 16 KB
  u32 isf32 = flag[0];
  int tid = threadIdx.x, lane = tid & 63, wave = tid >> 6;
  int col = lane & 15, quad = lane >> 4;
  int r0 = blockIdx.x * 64;

  // phase 1: Z = relu(u @ Wa + ba), u = [x|hz], tile 64 x 256 (waves split 256 cols)
  f4 acc[4][4] = {};
  for (int kk = 0; kk < 8; ++kk) {
    int k0 = kk * 32;
    const void* src = (kk < 4) ? x : hz;
    int csrc = (kk < 4) ? k0 : (k0 - 128);
    __syncthreads();
    {  // stage A 64x32 with dtype convert: thread -> row=tid>>2, 8-col seg
      int row = tid >> 2, c0 = (tid & 3) * 8;
      size_t g = (size_t)(r0 + row) * 128 + csrc + c0;
      uint4 pk;
      if (isf32) {
        f4 v0 = *(const f4*)&((const float*)src)[g];
        f4 v1 = *(const f4*)&((const float*)src)[g + 4];
        pk.x = (u32)f2bf(v0[0]) | ((u32)f2bf(v0[1]) << 16);
        pk.y = (u32)f2bf(v0[2]) | ((u32)f2bf(v0[3]) << 16);
        pk.z = (u32)f2bf(v1[0]) | ((u32)f2bf(v1[1]) << 16);
        pk.w = (u32)f2bf(v1[2]) | ((u32)f2bf(v1[3]) << 16);
      } else {
        pk = *(const uint4*)&((const u16*)src)[g];
      }
      *(uint4*)&lA[row * 32 + c0] = pk;
    }
    stage128x32(WaT + k0, 256, lB, wave, lane);                       // o rows 0..127
    stage128x32(WaT + (size_t)128 * 256 + k0, 256, lB + 4096, wave, lane); // o 128..255
    __syncthreads();
    bf8 af[4], bfr[4];
#pragma unroll
    for (int mi = 0; mi < 4; ++mi) af[mi] = *(const bf8*)&lA[(mi * 16 + col) * 32 + quad * 8];
#pragma unroll
    for (int nj = 0; nj < 4; ++nj) bfr[nj] = *(const bf8*)&lB[(wave * 64 + nj * 16 + col) * 32 + quad * 8];
#pragma unroll
    for (int mi = 0; mi < 4; ++mi)
#pragma unroll
      for (int nj = 0; nj < 4; ++nj)
        acc[mi][nj] = __builtin_amdgcn_mfma_f32_16x16x32_bf16(af[mi], bfr[nj], acc[mi][nj], 0, 0, 0);
  }
  // epilogue 1: Z[row][o] = relu(acc + ba[o])
#pragma unroll
  for (int mi = 0; mi < 4; ++mi)
#pragma unroll
    for (int nj = 0; nj < 4; ++nj) {
      int o = wave * 64 + nj * 16 + col;
      float bav = ldf(ba, o, isf32);
      int rl = mi * 16 + quad * 4;
#pragma unroll
      for (int r = 0; r < 4; ++r)
        Z[(rl + r) * 264 + o] = f2bf(fmaxf(acc[mi][nj][r] + bav, 0.f));
    }
  __syncthreads();

  // phase 2: D = tanh(Z @ Wb + bb); A-frags straight from Z (stride 264 -> 2-way only)
  f4 acc2[4][2] = {};
  for (int kk = 0; kk < 8; ++kk) {
    int k0 = kk * 32;
    if (kk) __syncthreads();
    stage128x32(WbT + k0, 256, lB, wave, lane);   // d rows 0..127
    __syncthreads();
    bf8 az[4], bw[2];
#pragma unroll
    for (int mi = 0; mi < 4; ++mi) az[mi] = *(const bf8*)&Z[(mi * 16 + col) * 264 + k0 + quad * 8];
#pragma unroll
    for (int nj = 0; nj < 2; ++nj) bw[nj] = *(const bf8*)&lB[(wave * 32 + nj * 16 + col) * 32 + quad * 8];
#pragma unroll
    for (int mi = 0; mi < 4; ++mi)
#pragma unroll
      for (int nj = 0; nj < 2; ++nj)
        acc2[mi][nj] = __builtin_amdgcn_mfma_f32_16x16x32_bf16(az[mi], bw[nj], acc2[mi][nj], 0, 0, 0);
  }
  // epilogue 2: tanh(+bb), transposed pack-4 store hT[(b*128+d)][n..n+3]
#pragma unroll
  for (int mi = 0; mi < 4; ++mi)
#pragma unroll
    for (int nj = 0; nj < 2; ++nj) {
      int d = wave * 32 + nj * 16 + col;
      float bbv = ldf(bb, d, isf32);
      int rabs = r0 + mi * 16 + quad * 4;   // 4 consecutive global rows, same b
      int b = rabs >> 11, n = rabs & 2047;
      u16 p[4];
#pragma unroll
      for (int r = 0; r < 4; ++r) p[r] = f2bf(tanhf(acc2[mi][nj][r] + bbv));
      u64 pk = (u64)p[0] | ((u64)p[1] << 16) | ((u64)p[2] << 32) | ((u64)p[3] << 48);
      *(u64*)&hT[(size_t)(b * 128 + d) * 2048 + n] = pk;
    }
}

// ---------------- fused diffusion step (double-buffered K-loop) ----------------
// Pass 1 (gemm_bt): G_T[c=(b,d)][n2] = sum_k hin[c][k] * adjb[n2][k]   (128x128, K=2048)
// Pass 2 (in-LDS):  M[j][n] = sum_d WT[j][d] * G_T[b*128+d][n]         (K=128)
// Epilogue: nh = hold + DT*tanh(M); (eps step: *= clip(eps,0,0.1)); write half;
//           copy untouched half (ping-pong buffers avoid cross-block RAW race).
__global__ __launch_bounds__(256, 2) void fused_step(const u16* __restrict__ hin,
                                                     const u16* __restrict__ adjb,
                                                     const u16* __restrict__ WT,
                                                     const void* __restrict__ eps,
                                                     u16* __restrict__ hout,
                                                     int half, const u32* __restrict__ flag) {
  __shared__ __align__(16) u16 lA[2][128 * 32];
  __shared__ __align__(16) u16 lB[2][128 * 32];
  __shared__ __align__(16) u16 gT[128 * 136];
  u32 isf32 = flag[0];
  int tid = threadIdx.x, lane = tid & 63, wave = tid >> 6;
  int wm = wave >> 1, wn = wave & 1, col = lane & 15, quad = lane >> 4;
  int b = blockIdx.y;
  int n0 = blockIdx.x * 128;

  const u16* Arow = hin + (size_t)(b * 128) * 2048;
  const u16* Brow = adjb + (size_t)n0 * 2048;

  // prologue: stage tile 0 into buffer 0
  stage128x32(Arow, 2048, lA[0], wave, lane);
  stage128x32(Brow, 2048, lB[0], wave, lane);
  __syncthreads();   // drains vmcnt(0): tile 0 resident

  f4 acc[4][4] = {};
  for (int kk = 0; kk < 64; ++kk) {
    int cur = kk & 1;
    // issue next tile's async loads FIRST: they stay in flight across this compute
    if (kk < 63) {
      stage128x32(Arow + (kk + 1) * 32, 2048, lA[cur ^ 1], wave, lane);
      stage128x32(Brow + (kk + 1) * 32, 2048, lB[cur ^ 1], wave, lane);
    }
    bf8 af[4], bfr[4];
#pragma unroll
    for (int mi = 0; mi < 4; ++mi) af[mi] = *(const bf8*)&lA[cur][(wm * 64 + mi * 16 + col) * 32 + quad * 8];
#pragma unroll
    for (int nj = 0; nj < 4; ++nj) bfr[nj] = *(const bf8*)&lB[cur][(wn * 64 + nj * 16 + col) * 32 + quad * 8];
#pragma unroll
    for (int mi = 0; mi < 4; ++mi)
#pragma unroll
      for (int nj = 0; nj < 4; ++nj)
        acc[mi][nj] = __builtin_amdgcn_mfma_f32_16x16x32_bf16(af[mi], bfr[nj], acc[mi][nj], 0, 0, 0);
    __syncthreads();  // all waves done reading cur; next-tile loads drained
  }
  // dump acc tile to LDS transposed: gT[n][d] (separate region; barrier above suffices)
#pragma unroll
  for (int mi = 0; mi < 4; ++mi)
#pragma unroll
    for (int nj = 0; nj < 4; ++nj) {
      int d0 = wm * 64 + mi * 16 + quad * 4;
      int nl = wn * 64 + nj * 16 + col;
      u32 lo = (u32)f2bf(acc[mi][nj][0]) | ((u32)f2bf(acc[mi][nj][1]) << 16);
      u32 hi = (u32)f2bf(acc[mi][nj][2]) | ((u32)f2bf(acc[mi][nj][3]) << 16);
      *(u64*)&gT[nl * 136 + d0] = (u64)lo | ((u64)hi << 32);
    }
  __syncthreads();

  f4 acc2[4][2] = {};
#pragma unroll
  for (int k2 = 0; k2 < 4; ++k2) {
    bf8 aw[4], bg[2];
#pragma unroll
    for (int mi = 0; mi < 4; ++mi)
      aw[mi] = *(const bf8*)&WT[(size_t)(mi * 16 + col) * 128 + k2 * 32 + quad * 8];
#pragma unroll
    for (int nj = 0; nj < 2; ++nj)
      bg[nj] = *(const bf8*)&gT[(wave * 32 + nj * 16 + col) * 136 + k2 * 32 + quad * 8];
#pragma unroll
    for (int mi = 0; mi < 4; ++mi)
#pragma unroll
      for (int nj = 0; nj < 2; ++nj)
        acc2[mi][nj] = __builtin_amdgcn_mfma_f32_16x16x32_bf16(aw[mi], bg[nj], acc2[mi][nj], 0, 0, 0);
  }

  bool has_eps = (eps != nullptr);
#pragma unroll
  for (int mi = 0; mi < 4; ++mi)
#pragma unroll
    for (int nj = 0; nj < 2; ++nj) {
      int j0 = mi * 16 + quad * 4;
      int nl = wave * 32 + nj * 16 + col;
      int n = n0 + nl;
      float ev[4];
      if (has_eps) {
        size_t eoff = ((size_t)b * 2048 + n) * 64 + j0;
        if (isf32) {
          f4 e = *(const f4*)&((const float*)eps)[eoff];
          ev[0] = e[0]; ev[1] = e[1]; ev[2] = e[2]; ev[3] = e[3];
        } else {
          u64 e = *(const u64*)&((const u16*)eps)[eoff];
          ev[0] = bf2f((u16)e); ev[1] = bf2f((u16)(e >> 16));
          ev[2] = bf2f((u16)(e >> 32)); ev[3] = bf2f((u16)(e >> 48));
        }
      }
#pragma unroll
      for (int r = 0; r < 4; ++r) {
        int j = j0 + r;
        size_t idx = (size_t)(b * 128 + half * 64 + j) * 2048 + n;
        float hold = bf2f(hin[idx]);
        float nh = hold + 0.01f * tanhf(acc2[mi][nj][r]);
        if (has_eps) {
          float e = fminf(fmaxf(ev[r], 0.f), 0.1f);  // clip in fp32
          nh = e * nh;
        }
        hout[idx] = f2bf(nh);
      }
    }

  // copy the untouched half for this (b, n-tile)
  {
    int oh = (1 - half) * 64;
    const u16* src = hin + (size_t)(b * 128 + oh) * 2048 + n0;
    u16* dst = hout + (size_t)(b * 128 + oh) * 2048 + n0;
#pragma unroll
    for (int i = 0; i < 4; ++i) {
      int idx = i * 256 + tid;
      int rr = idx >> 4;
      int cc = (idx & 15) * 8;
      *(uint4*)&dst[(size_t)rr * 2048 + cc] = *(const uint4*)&src[(size_t)rr * 2048 + cc];
    }
  }
}

// ---------------- final un-transpose: out[b][n][d] = hT[(b*128+d)][n], dtype-aware ----
__global__ void untranspose(const u16* __restrict__ hT, void* __restrict__ out,
                            const u32* __restrict__ flag) {
  __shared__ __align__(16) u16 t[64][65];
  u32 isf32 = flag[0];
  int b = blockIdx.z, d0 = blockIdx.y * 64, n0 = blockIdx.x * 64;
  int tid = threadIdx.x;
#pragma unroll
  for (int i = 0; i < 16; ++i) {
    int idx = tid + i * 256;
    int r = idx >> 6, c = idx & 63;
    t[r][c] = hT[(size_t)(b * 128 + d0 + r) * 2048 + n0 + c];
  }
  __syncthreads();
#pragma unroll
  for (int i = 0; i < 16; ++i) {
    int idx = tid + i * 256;
    int r = idx >> 6, c = idx & 63;  // r = n-local, c = d-local
    size_t o = (size_t)(b * 2048 + n0 + r) * 128 + d0 + c;
    if (isf32) ((float*)out)[o] = bf2f(t[c][r]);
    else       ((u16*)out)[o] = t[c][r];
  }
}

extern "C" void kernel_launch(void* const* d_in, const int* in_sizes, int n_in,
                              void* d_out, int out_size, void* d_ws, size_t ws_size,
                              hipStream_t stream) {
  const void* x   = d_in[0];
  const void* hz  = d_in[1];
  const void* adj = d_in[2];
  const void* W1  = d_in[3];
  const void* W2  = d_in[4];
  const void* Wa  = d_in[5];
  const void* ba  = d_in[6];
  const void* Wb  = d_in[7];
  const void* bb  = d_in[8];
  const void* eps = d_in[9];

  // workspace layout (26.3 MB):
  //   hA   @  0M   16.78 MB  transposed h ping buffer (bf16 [4096][2048])
  //   adjb @ 17M    8.39 MB  adj bf16 [2048][2048]
  //   WaT/WbT/W1T/W2T @ 26M (229 KB), flag after
  // hB (pong) = d_out scratch; untranspose fully rewrites d_out at the end.
  char* ws = (char*)d_ws;
  u16* hA   = (u16*)(ws);
  u16* adjb = (u16*)(ws + (17ull << 20));
  u16* WaT  = (u16*)(ws + (26ull << 20));
  u16* WbT  = WaT + 256 * 256;
  u16* W1T  = WbT + 128 * 256;
  u16* W2T  = W1T + 64 * 128;
  u32* flag = (u32*)(W2T + 64 * 128);
  u16* hB   = (u16*)d_out;

  detect_dtype<<<dim3(1), dim3(256), 0, stream>>>((const u16*)x, flag);
  prep_weights<<<dim3(448), dim3(256), 0, stream>>>(Wa, Wb, W1, W2, WaT, WbT, W1T, W2T, flag);
  cvt_bf16<<<dim3(4096), dim3(256), 0, stream>>>(adj, adjb, 0, 4194304, flag);
  mlp_fused<<<dim3(1024), dim3(256), 0, stream>>>(x, hz, WaT, ba, WbT, bb, hA, flag);
  // iter 1
  fused_step<<<dim3(16, 32), dim3(256), 0, stream>>>(hA, adjb, W1T, nullptr, hB, 0, flag);
  fused_step<<<dim3(16, 32), dim3(256), 0, stream>>>(hB, adjb, W2T, eps, hA, 1, flag);
  // iter 2
  fused_step<<<dim3(16, 32), dim3(256), 0, stream>>>(hA, adjb, W1T, nullptr, hB, 0, flag);
  fused_step<<<dim3(16, 32), dim3(256), 0, stream>>>(hB, adjb, W2T, eps, hA, 1, flag);
  untranspose<<<dim3(32, 2, 32), dim3(256), 0, stream>>>(hA, d_out, flag);
}

// Round 5
// 350.054 us; speedup vs baseline: 1.4440x; 1.1773x over previous
//
#include <hip/hip_runtime.h>

// GODE on MI355X. bf16 MFMA, fp32 accum, h TRANSPOSED: hT[(b*128+d)][n].
// R5 algebra: (adj@h)@W_half == adj@(h@W_half)  -> big GEMM per step is
// [64 j x 2048 n2, K=2048] per batch (17.2 GF/step, half of before). hW (h@W_half,
// transposed layout hWT[(b*64+j)][n], [2048][2048]) is produced in the PREVIOUS
// kernel's epilogue (mlp_fused for step 1; fused_step2 for steps 2..4) via the
// proven in-LDS pass-2 structure. Big-GEMM K-loop uses BK=128 (4x 32-col panels,
// [rows][32] LDS layout each) -> 16 latency-bound iterations instead of 64.

typedef unsigned short u16;
typedef unsigned int   u32;
typedef unsigned long long u64;
typedef __attribute__((ext_vector_type(8))) short bf8;  // 8 raw bf16 (4 VGPRs)
typedef __attribute__((ext_vector_type(4))) float f4;

#define AS1 __attribute__((address_space(1)))
#define AS3 __attribute__((address_space(3)))

__device__ __forceinline__ void gl_lds16(const void* g, void* l) {
  __builtin_amdgcn_global_load_lds((const AS1 u32*)g, (AS3 u32*)l, 16, 0, 0);
}
__device__ __forceinline__ float bf2f(u16 v) {
  u32 u = ((u32)v) << 16; return __builtin_bit_cast(float, u);
}
__device__ __forceinline__ u16 f2bf(float f) {  // RNE
  u32 u = __builtin_bit_cast(u32, f);
  return (u16)((u + 0x7fffu + ((u >> 16) & 1u)) >> 16);
}
__device__ __forceinline__ float ldf(const void* p, size_t i, u32 isf32) {
  return isf32 ? ((const float*)p)[i] : bf2f(((const u16*)p)[i]);
}

// Stage 128x32 bf16 tile (row stride `stride`) into LDS [128][32]; 2 calls/wave.
__device__ __forceinline__ void stage128x32(const u16* grow0, int stride, u16* lds,
                                            int wave, int lane) {
  int r0 = wave * 16 + (lane >> 2);
  int c0 = (lane & 3) * 8;
  gl_lds16(grow0 + (size_t)r0 * stride + c0, lds + wave * 512);
  gl_lds16(grow0 + (size_t)(64 + r0) * stride + c0, lds + 2048 + wave * 512);
}
// Stage 64x32 tile into LDS [64][32]; 1 call/wave.
__device__ __forceinline__ void stage64x32(const u16* grow0, int stride, u16* lds,
                                           int wave, int lane) {
  gl_lds16(grow0 + (size_t)(wave * 16 + (lane >> 2)) * stride + (lane & 3) * 8,
           lds + wave * 512);
}

// ---------------- dtype detection ----------------
__global__ void detect_dtype(const u16* __restrict__ x_raw, u32* __restrict__ flag) {
  __shared__ int s;
  int tid = threadIdx.x;
  if (tid == 0) s = 0;
  __syncthreads();
  int huge = 0;
#pragma unroll
  for (int j = 0; j < 16; ++j) {
    u16 v = x_raw[tid * 16 + j];
    u32 e = (v >> 7) & 0xFF;
    if (e >= 0xC0) huge = 1;          // |v| >= 2^64: impossible for N(0,1) bf16
  }
  if (huge) atomicOr(&s, 1);
  __syncthreads();
  if (tid == 0) flag[0] = (u32)s;     // 1 = f32 inputs, 0 = bf16 inputs
}

// ---------------- generic convert to bf16 (adj) ----------------
__global__ void cvt_bf16(const void* __restrict__ in, u16* __restrict__ out,
                         long in_off, int n, const u32* __restrict__ flag) {
  u32 isf32 = flag[0];
  int gid = blockIdx.x * 256 + threadIdx.x;
  long i = in_off + (long)gid * 4;
  if (gid * 4 >= n) return;
  u16 o0, o1, o2, o3;
  if (isf32) {
    f4 v = *(const f4*)&((const float*)in)[i];
    o0 = f2bf(v[0]); o1 = f2bf(v[1]); o2 = f2bf(v[2]); o3 = f2bf(v[3]);
  } else {
    u64 v = *(const u64*)&((const u16*)in)[i];
    o0 = (u16)v; o1 = (u16)(v >> 16); o2 = (u16)(v >> 32); o3 = (u16)(v >> 48);
  }
  u64 pk = (u64)o0 | ((u64)o1 << 16) | ((u64)o2 << 32) | ((u64)o3 << 48);
  *(u64*)&out[(size_t)gid * 4] = pk;
}

// ---------------- weight pre-transpose ----------------
// WaT[256][256]=Wa^T, WbT[128][256]=Wb^T, W1T[64][128]=W1[:, :64]^T, W2T[64][128]=W2[:, 64:]^T
__global__ void prep_weights(const void* __restrict__ Wa, const void* __restrict__ Wb,
                             const void* __restrict__ W1, const void* __restrict__ W2,
                             u16* __restrict__ WaT, u16* __restrict__ WbT,
                             u16* __restrict__ W1T, u16* __restrict__ W2T,
                             const u32* __restrict__ flag) {
  u32 isf32 = flag[0];
  int i = blockIdx.x * 256 + threadIdx.x;
  if (i < 65536) {
    int o = i >> 8, k = i & 255; WaT[o * 256 + k] = f2bf(ldf(Wa, (size_t)k * 256 + o, isf32));
  } else if (i < 98304) {
    int j = i - 65536; int o = j >> 8, k = j & 255;
    WbT[o * 256 + k] = f2bf(ldf(Wb, (size_t)k * 128 + o, isf32));
  } else if (i < 106496) {
    int j = i - 98304; int jj = j >> 7, k = j & 127;
    W1T[jj * 128 + k] = f2bf(ldf(W1, (size_t)k * 128 + jj, isf32));
  } else {
    int j = i - 106496; int jj = j >> 7, k = j & 127;
    W2T[jj * 128 + k] = f2bf(ldf(W2, (size_t)k * 128 + 64 + jj, isf32));
  }
}

// ---------------- fused MLP + first hW ----------------
// hT = tanh(relu([x,hz]@Wa+ba)@Wb+bb)  (transposed store), and
// hW1T[(b*64+j)][n] = sum_d W1T[j][d] * h0[n-row][d]  (epilogue in-LDS GEMM).
__global__ __launch_bounds__(256, 2) void mlp_fused(const void* __restrict__ x,
                                                    const void* __restrict__ hz,
                                                    const u16* __restrict__ WaT,
                                                    const void* __restrict__ ba,
                                                    const u16* __restrict__ WbT,
                                                    const void* __restrict__ bb,
                                                    const u16* __restrict__ W1T,
                                                    u16* __restrict__ hT,
                                                    u16* __restrict__ hW,
                                                    const u32* __restrict__ flag) {
  __shared__ __align__(16) u16 Z[64 * 264];     // 33.8 KB
  __shared__ __align__(16) u16 pool[10240];     // 20 KB: lA 64x32 | lB 256x32; later hN 64x136
  u16* lA = pool;
  u16* lB = pool + 2048;
  u16* hN = pool;                               // 64*136 = 8704 u16, overlays lA/lB post-use
  u32 isf32 = flag[0];
  int tid = threadIdx.x, lane = tid & 63, wave = tid >> 6;
  int col = lane & 15, quad = lane >> 4;
  int r0 = blockIdx.x * 64;
  int b = r0 >> 11;

  // phase 1: Z = relu(u @ Wa + ba), u = [x|hz], tile 64 x 256 (waves split 256 o-cols)
  f4 acc[4][4] = {};
  for (int kk = 0; kk < 8; ++kk) {
    int k0 = kk * 32;
    const void* src = (kk < 4) ? x : hz;
    int csrc = (kk < 4) ? k0 : (k0 - 128);
    __syncthreads();
    {  // stage A 64x32 with dtype convert
      int row = tid >> 2, c0 = (tid & 3) * 8;
      size_t g = (size_t)(r0 + row) * 128 + csrc + c0;
      uint4 pk;
      if (isf32) {
        f4 v0 = *(const f4*)&((const float*)src)[g];
        f4 v1 = *(const f4*)&((const float*)src)[g + 4];
        pk.x = (u32)f2bf(v0[0]) | ((u32)f2bf(v0[1]) << 16);
        pk.y = (u32)f2bf(v0[2]) | ((u32)f2bf(v0[3]) << 16);
        pk.z = (u32)f2bf(v1[0]) | ((u32)f2bf(v1[1]) << 16);
        pk.w = (u32)f2bf(v1[2]) | ((u32)f2bf(v1[3]) << 16);
      } else {
        pk = *(const uint4*)&((const u16*)src)[g];
      }
      *(uint4*)&lA[row * 32 + c0] = pk;
    }
    stage128x32(WaT + k0, 256, lB, wave, lane);
    stage128x32(WaT + (size_t)128 * 256 + k0, 256, lB + 4096, wave, lane);
    __syncthreads();
    bf8 af[4], bfr[4];
#pragma unroll
    for (int mi = 0; mi < 4; ++mi) af[mi] = *(const bf8*)&lA[(mi * 16 + col) * 32 + quad * 8];
#pragma unroll
    for (int nj = 0; nj < 4; ++nj) bfr[nj] = *(const bf8*)&lB[(wave * 64 + nj * 16 + col) * 32 + quad * 8];
#pragma unroll
    for (int mi = 0; mi < 4; ++mi)
#pragma unroll
      for (int nj = 0; nj < 4; ++nj)
        acc[mi][nj] = __builtin_amdgcn_mfma_f32_16x16x32_bf16(af[mi], bfr[nj], acc[mi][nj], 0, 0, 0);
  }
#pragma unroll
  for (int mi = 0; mi < 4; ++mi)
#pragma unroll
    for (int nj = 0; nj < 4; ++nj) {
      int o = wave * 64 + nj * 16 + col;
      float bav = ldf(ba, o, isf32);
      int rl = mi * 16 + quad * 4;
#pragma unroll
      for (int r = 0; r < 4; ++r)
        Z[(rl + r) * 264 + o] = f2bf(fmaxf(acc[mi][nj][r] + bav, 0.f));
    }
  __syncthreads();

  // phase 2: h0 = tanh(Z @ Wb + bb); A-frags from Z (stride 264)
  f4 acc2[4][2] = {};
  for (int kk = 0; kk < 8; ++kk) {
    int k0 = kk * 32;
    if (kk) __syncthreads();
    stage128x32(WbT + k0, 256, lB, wave, lane);
    __syncthreads();
    bf8 az[4], bw[2];
#pragma unroll
    for (int mi = 0; mi < 4; ++mi) az[mi] = *(const bf8*)&Z[(mi * 16 + col) * 264 + k0 + quad * 8];
#pragma unroll
    for (int nj = 0; nj < 2; ++nj) bw[nj] = *(const bf8*)&lB[(wave * 32 + nj * 16 + col) * 32 + quad * 8];
#pragma unroll
    for (int mi = 0; mi < 4; ++mi)
#pragma unroll
      for (int nj = 0; nj < 2; ++nj)
        acc2[mi][nj] = __builtin_amdgcn_mfma_f32_16x16x32_bf16(az[mi], bw[nj], acc2[mi][nj], 0, 0, 0);
  }
  __syncthreads();   // all waves done with lB before hN overlay

  // epilogue: tanh(+bb) -> global hT (transposed) AND hN[r][d] staging for hW1
#pragma unroll
  for (int mi = 0; mi < 4; ++mi)
#pragma unroll
    for (int nj = 0; nj < 2; ++nj) {
      int d = wave * 32 + nj * 16 + col;
      float bbv = ldf(bb, d, isf32);
      int rl = mi * 16 + quad * 4;
      int rabs = r0 + rl;
      int n = rabs & 2047;
      u16 p[4];
#pragma unroll
      for (int r = 0; r < 4; ++r) {
        p[r] = f2bf(tanhf(acc2[mi][nj][r] + bbv));
        hN[(rl + r) * 136 + d] = p[r];
      }
      u64 pk = (u64)p[0] | ((u64)p[1] << 16) | ((u64)p[2] << 32) | ((u64)p[3] << 48);
      *(u64*)&hT[(size_t)(b * 128 + d) * 2048 + n] = pk;
    }
  __syncthreads();

  // hW1: out[j][r] = sum_d W1T[j][d] * hN[r][d]; wave covers r in [wave*16, wave*16+16)
  f4 acc3[4] = {};
#pragma unroll
  for (int ks = 0; ks < 4; ++ks) {
    bf8 aw[4], bg;
#pragma unroll
    for (int mi = 0; mi < 4; ++mi)
      aw[mi] = *(const bf8*)&W1T[(size_t)(mi * 16 + col) * 128 + ks * 32 + quad * 8];
    bg = *(const bf8*)&hN[(wave * 16 + col) * 136 + ks * 32 + quad * 8];
#pragma unroll
    for (int mi = 0; mi < 4; ++mi)
      acc3[mi] = __builtin_amdgcn_mfma_f32_16x16x32_bf16(aw[mi], bg, acc3[mi], 0, 0, 0);
  }
#pragma unroll
  for (int mi = 0; mi < 4; ++mi) {
    int rloc = wave * 16 + col;
    int ng = (r0 & 2047) + rloc;
#pragma unroll
    for (int r = 0; r < 4; ++r) {
      int j = mi * 16 + quad * 4 + r;
      hW[(size_t)(b * 64 + j) * 2048 + ng] = f2bf(acc3[mi][r]);
    }
  }
}

// ---------------- fused diffusion step (v2: W-first algebra, BK=128) ----------------
// Big GEMM: G[m=(b,j)][n2] = sum_n hWT[(b*64+j)][n] * adjb[n2][n]  (64x128 tile, K=2048)
// Update: nh = hin + DT*tanh(G)  (eps step: *= clip(eps,0,0.1)); write updated half +
// copy untouched half to hout. If WnT: stage hnew into gN[n][d] and produce next
// hWout[(b*64+j')][n] = sum_d WnT[j'][d] * gN[n][d]  (in-LDS pass-2).
__global__ __launch_bounds__(256, 2) void fused_step2(const u16* __restrict__ hin,
                                                      const u16* __restrict__ hWT,
                                                      const u16* __restrict__ adjb,
                                                      const u16* __restrict__ WnT,
                                                      const void* __restrict__ eps,
                                                      u16* __restrict__ hout,
                                                      u16* __restrict__ hWout,
                                                      int half, const u32* __restrict__ flag) {
  __shared__ __align__(16) u16 smem[24576];   // 48 KB
  u16* lA = smem;               // 4 panels x [64][32]
  u16* lB = smem + 8192;        // 4 panels x [128][32]
  u16* gN = smem;               // [128][136] = 17408 u16, overlays lA/lB post K-loop
  u32 isf32 = flag[0];
  int tid = threadIdx.x, lane = tid & 63, wave = tid >> 6;
  int col = lane & 15, quad = lane >> 4;
  int b = blockIdx.y;
  int n0 = blockIdx.x * 128;

  const u16* Arow = hWT + (size_t)(b * 64) * 2048;
  const u16* Brow = adjb + (size_t)n0 * 2048;

  f4 acc[4][2] = {};
  for (int kk = 0; kk < 16; ++kk) {
    int k0 = kk * 128;
#pragma unroll
    for (int p = 0; p < 4; ++p) {
      stage64x32(Arow + k0 + p * 32, 2048, lA + p * 2048, wave, lane);
      stage128x32(Brow + k0 + p * 32, 2048, lB + p * 4096, wave, lane);
    }
    __syncthreads();
#pragma unroll
    for (int p = 0; p < 4; ++p) {
      bf8 af[4], bfr[2];
#pragma unroll
      for (int mi = 0; mi < 4; ++mi) af[mi] = *(const bf8*)&lA[p * 2048 + (mi * 16 + col) * 32 + quad * 8];
#pragma unroll
      for (int nj = 0; nj < 2; ++nj) bfr[nj] = *(const bf8*)&lB[p * 4096 + (wave * 32 + nj * 16 + col) * 32 + quad * 8];
#pragma unroll
      for (int mi = 0; mi < 4; ++mi)
#pragma unroll
        for (int nj = 0; nj < 2; ++nj)
          acc[mi][nj] = __builtin_amdgcn_mfma_f32_16x16x32_bf16(af[mi], bfr[nj], acc[mi][nj], 0, 0, 0);
    }
    __syncthreads();
  }

  bool has_eps = (eps != nullptr);
  bool mk_hw = (WnT != nullptr);
  int dBase = half * 64;
  // update + write updated half; stage nh into gN[n][dBase+j]
#pragma unroll
  for (int mi = 0; mi < 4; ++mi)
#pragma unroll
    for (int nj = 0; nj < 2; ++nj) {
      int j0 = mi * 16 + quad * 4;
      int nl = wave * 32 + nj * 16 + col;
      int n = n0 + nl;
      float ev[4];
      if (has_eps) {
        size_t eoff = ((size_t)b * 2048 + n) * 64 + j0;
        if (isf32) {
          f4 e = *(const f4*)&((const float*)eps)[eoff];
          ev[0] = e[0]; ev[1] = e[1]; ev[2] = e[2]; ev[3] = e[3];
        } else {
          u64 e = *(const u64*)&((const u16*)eps)[eoff];
          ev[0] = bf2f((u16)e); ev[1] = bf2f((u16)(e >> 16));
          ev[2] = bf2f((u16)(e >> 32)); ev[3] = bf2f((u16)(e >> 48));
        }
      }
      u16 pv[4];
#pragma unroll
      for (int r = 0; r < 4; ++r) {
        int j = j0 + r;
        size_t idx = (size_t)(b * 128 + dBase + j) * 2048 + n;
        float hold = bf2f(hin[idx]);
        float nh = hold + 0.01f * tanhf(acc[mi][nj][r]);
        if (has_eps) {
          float e = fminf(fmaxf(ev[r], 0.f), 0.1f);
          nh = e * nh;
        }
        pv[r] = f2bf(nh);
        hout[idx] = pv[r];
      }
      if (mk_hw) {
        u64 pk = (u64)pv[0] | ((u64)pv[1] << 16) | ((u64)pv[2] << 32) | ((u64)pv[3] << 48);
        *(u64*)&gN[nl * 136 + dBase + j0] = pk;
      }
    }

  // copy untouched half to hout; also scatter into gN[n][oh+row]
  {
    int oh = (1 - half) * 64;
    const u16* src = hin + (size_t)(b * 128 + oh) * 2048 + n0;
    u16* dst = hout + (size_t)(b * 128 + oh) * 2048 + n0;
#pragma unroll
    for (int i = 0; i < 4; ++i) {
      int idx = i * 256 + tid;
      int rr = idx >> 4;
      int cc = (idx & 15) * 8;
      uint4 v = *(const uint4*)&src[(size_t)rr * 2048 + cc];
      *(uint4*)&dst[(size_t)rr * 2048 + cc] = v;
      if (mk_hw) {
        u16 t[8];
        *(uint4*)t = v;
#pragma unroll
        for (int q = 0; q < 8; ++q) gN[(cc + q) * 136 + oh + rr] = t[q];
      }
    }
  }

  if (mk_hw) {
    __syncthreads();
    // next hW: out[j'][n] = sum_d WnT[j'][d] * gN[n][d]
    f4 acc2[4][2] = {};
#pragma unroll
    for (int ks = 0; ks < 4; ++ks) {
      bf8 aw[4], bg[2];
#pragma unroll
      for (int mi = 0; mi < 4; ++mi)
        aw[mi] = *(const bf8*)&WnT[(size_t)(mi * 16 + col) * 128 + ks * 32 + quad * 8];
#pragma unroll
      for (int nj = 0; nj < 2; ++nj)
        bg[nj] = *(const bf8*)&gN[(wave * 32 + nj * 16 + col) * 136 + ks * 32 + quad * 8];
#pragma unroll
      for (int mi = 0; mi < 4; ++mi)
#pragma unroll
        for (int nj = 0; nj < 2; ++nj)
          acc2[mi][nj] = __builtin_amdgcn_mfma_f32_16x16x32_bf16(aw[mi], bg[nj], acc2[mi][nj], 0, 0, 0);
    }
#pragma unroll
    for (int mi = 0; mi < 4; ++mi)
#pragma unroll
      for (int nj = 0; nj < 2; ++nj) {
        int jp0 = mi * 16 + quad * 4;
        int n = n0 + wave * 32 + nj * 16 + col;
#pragma unroll
        for (int r = 0; r < 4; ++r)
          hWout[(size_t)(b * 64 + jp0 + r) * 2048 + n] = f2bf(acc2[mi][nj][r]);
      }
  }
}

// ---------------- final un-transpose: out[b][n][d] = hT[(b*128+d)][n] ----------------
__global__ void untranspose(const u16* __restrict__ hT, void* __restrict__ out,
                            const u32* __restrict__ flag) {
  __shared__ __align__(16) u16 t[64][65];
  u32 isf32 = flag[0];
  int b = blockIdx.z, d0 = blockIdx.y * 64, n0 = blockIdx.x * 64;
  int tid = threadIdx.x;
#pragma unroll
  for (int i = 0; i < 16; ++i) {
    int idx = tid + i * 256;
    int r = idx >> 6, c = idx & 63;
    t[r][c] = hT[(size_t)(b * 128 + d0 + r) * 2048 + n0 + c];
  }
  __syncthreads();
#pragma unroll
  for (int i = 0; i < 16; ++i) {
    int idx = tid + i * 256;
    int r = idx >> 6, c = idx & 63;  // r = n-local, c = d-local
    size_t o = (size_t)(b * 2048 + n0 + r) * 128 + d0 + c;
    if (isf32) ((float*)out)[o] = bf2f(t[c][r]);
    else       ((u16*)out)[o] = t[c][r];
  }
}

extern "C" void kernel_launch(void* const* d_in, const int* in_sizes, int n_in,
                              void* d_out, int out_size, void* d_ws, size_t ws_size,
                              hipStream_t stream) {
  const void* x   = d_in[0];
  const void* hz  = d_in[1];
  const void* adj = d_in[2];
  const void* W1  = d_in[3];
  const void* W2  = d_in[4];
  const void* Wa  = d_in[5];
  const void* ba  = d_in[6];
  const void* Wb  = d_in[7];
  const void* bb  = d_in[8];
  const void* eps = d_in[9];

  // workspace layout (44.3 MB):
  //   hA   @  0M   16.78 MB  transposed h ping buffer (bf16 [4096][2048])
  //   adjb @ 17M    8.39 MB  adj bf16 [2048][2048]
  //   hWa  @ 26M    8.39 MB  hW ping (bf16 [2048][2048])
  //   hWb  @ 35M    8.39 MB  hW pong
  //   weights @ 44M (229 KB), flag after
  // hB (pong h) = d_out scratch; untranspose fully rewrites d_out at the end.
  char* ws = (char*)d_ws;
  u16* hA   = (u16*)(ws);
  u16* adjb = (u16*)(ws + (17ull << 20));
  u16* hWa  = (u16*)(ws + (26ull << 20));
  u16* hWb  = (u16*)(ws + (35ull << 20));
  u16* WaT  = (u16*)(ws + (44ull << 20));
  u16* WbT  = WaT + 256 * 256;
  u16* W1T  = WbT + 128 * 256;
  u16* W2T  = W1T + 64 * 128;
  u32* flag = (u32*)(W2T + 64 * 128);
  u16* hB   = (u16*)d_out;

  detect_dtype<<<dim3(1), dim3(256), 0, stream>>>((const u16*)x, flag);
  prep_weights<<<dim3(448), dim3(256), 0, stream>>>(Wa, Wb, W1, W2, WaT, WbT, W1T, W2T, flag);
  cvt_bf16<<<dim3(4096), dim3(256), 0, stream>>>(adj, adjb, 0, 4194304, flag);
  mlp_fused<<<dim3(1024), dim3(256), 0, stream>>>(x, hz, WaT, ba, WbT, bb, W1T, hA, hWa, flag);
  // step 1 (half=0, consumes hWa=h0@W1h, produces hWb=h1@W2h)
  fused_step2<<<dim3(16, 32), dim3(256), 0, stream>>>(hA, hWa, adjb, W2T, nullptr, hB, hWb, 0, flag);
  // step 2 (half=1, eps; consumes hWb, produces hWa=h2@W1h)
  fused_step2<<<dim3(16, 32), dim3(256), 0, stream>>>(hB, hWb, adjb, W1T, eps, hA, hWa, 1, flag);
  // step 3 (half=0; consumes hWa, produces hWb=h3@W2h)
  fused_step2<<<dim3(16, 32), dim3(256), 0, stream>>>(hA, hWa, adjb, W2T, nullptr, hB, hWb, 0, flag);
  // step 4 (half=1, eps; consumes hWb, no next hW)
  fused_step2<<<dim3(16, 32), dim3(256), 0, stream>>>(hB, hWb, adjb, nullptr, eps, hA, nullptr, 1, flag);
  untranspose<<<dim3(32, 2, 32), dim3(256), 0, stream>>>(hA, d_out, flag);
}